// Round 6
// baseline (89.275 us; speedup 1.0000x reference)
//
#include <hip/hip_runtime.h>
#include <hip/hip_fp16.h>

// KirchhoffNet: out[n] = sum_{dst==n} cur - sum_{src==n} cur,
// cur = cond * relu(t1*(v[src]-v[dst]) + t2)
//
// Round 6: binned-entry pipeline, zero global atomics.
//  P0: stream edges, gather v (the ~40us divergent-gather wall), compute cur;
//      emit packed entry (local15|sign1|f16mag) per NONZERO endpoint into 4
//      node-range bins, staged in LDS, flushed to fixed per-(block,bin) slots.
//  P1: per (range, slice): LDS accumulator 128KiB, read ONLY this range's
//      entries (dense, ~12.8MB total across all), LDS atomics, dense flush.
//  P2: reduce NSLICE partial copies.

#define RANGE_LOG 15
#define RANGE     (1 << RANGE_LOG)      // 32768 nodes per range
#define NBIN      4                     // covers N <= 131072
#define P0_BLK    256
#define P0_EPT    4                     // edges per thread
#define P0_EPB    (P0_BLK * P0_EPT)     // 1024 edges per block
#define CAP       (2 * P0_EPB)          // 2048: max entries per (block,bin)
#define P1_BLK    1024
#define NSLICE    32

__global__ __launch_bounds__(P0_BLK) void p0_bin_kernel(
    const float* __restrict__ v,
    const int*   __restrict__ src,
    const int*   __restrict__ dst,
    const float* __restrict__ t1,
    const float* __restrict__ t2,
    const float* __restrict__ cond,
    unsigned*    __restrict__ bins,   // [NBIN][G][CAP]
    int*         __restrict__ cnt,    // [NBIN][G]
    int E, int G)
{
    __shared__ unsigned sbuf[NBIN][CAP];   // 32 KiB
    __shared__ int scnt[NBIN];

    if (threadIdx.x < NBIN) scnt[threadIdx.x] = 0;
    __syncthreads();

    const int blk = blockIdx.x;
    const int i0  = blk * P0_EPB + (int)threadIdx.x * P0_EPT;

    #define EMIT(node, mag, signbit)                                        \
        {                                                                   \
            int rr = (node) >> RANGE_LOG;                                   \
            unsigned lo = (unsigned)((node) & (RANGE - 1));                 \
            unsigned hb = (unsigned)__half_as_ushort(__float2half(mag));    \
            unsigned en = (lo << 17) | ((unsigned)(signbit) << 16) | hb;    \
            int idx = atomicAdd(&scnt[rr], 1);                              \
            sbuf[rr][idx] = en;                                             \
        }

    if (i0 + P0_EPT <= E) {
        int4   s4 = *(const int4*)  (src  + i0);
        int4   d4 = *(const int4*)  (dst  + i0);
        float4 a4 = *(const float4*)(t1   + i0);
        float4 b4 = *(const float4*)(t2   + i0);
        float4 c4 = *(const float4*)(cond + i0);

        // issue all 8 gathers before consuming
        float vs0 = v[s4.x], vs1 = v[s4.y], vs2 = v[s4.z], vs3 = v[s4.w];
        float vd0 = v[d4.x], vd1 = v[d4.y], vd2 = v[d4.z], vd3 = v[d4.w];

        float x0 = fmaf(a4.x, vs0 - vd0, b4.x);
        float x1 = fmaf(a4.y, vs1 - vd1, b4.y);
        float x2 = fmaf(a4.z, vs2 - vd2, b4.z);
        float x3 = fmaf(a4.w, vs3 - vd3, b4.w);

        if (x0 > 0.0f) { float c = c4.x * x0; EMIT(d4.x, c, 0u) EMIT(s4.x, c, 1u) }
        if (x1 > 0.0f) { float c = c4.y * x1; EMIT(d4.y, c, 0u) EMIT(s4.y, c, 1u) }
        if (x2 > 0.0f) { float c = c4.z * x2; EMIT(d4.z, c, 0u) EMIT(s4.z, c, 1u) }
        if (x3 > 0.0f) { float c = c4.w * x3; EMIT(d4.w, c, 0u) EMIT(s4.w, c, 1u) }
    } else {
        for (int i = i0; i < E; ++i) {
            int s = src[i], d = dst[i];
            float x = fmaf(t1[i], v[s] - v[d], t2[i]);
            if (x > 0.0f) { float c = cond[i] * x; EMIT(d, c, 0u) EMIT(s, c, 1u) }
        }
    }
    #undef EMIT

    __syncthreads();
    // flush: fixed slot per (block,bin), coalesced, no global atomics
    for (int r = 0; r < NBIN; ++r) {
        int c = scnt[r];
        unsigned* g = bins + ((size_t)r * G + blk) * CAP;
        for (int j = threadIdx.x; j < c; j += P0_BLK) g[j] = sbuf[r][j];
    }
    if (threadIdx.x < NBIN) cnt[threadIdx.x * G + blk] = scnt[threadIdx.x];
}

__global__ __launch_bounds__(P1_BLK) void p1_accum_kernel(
    const unsigned* __restrict__ bins,   // [NBIN][G][CAP]
    const int*      __restrict__ cnt,    // [NBIN][G]
    float*          __restrict__ partial,// [NSLICE][N]
    int N, int G)
{
    __shared__ __align__(16) float acc[RANGE];   // 128 KiB

    const int r    = blockIdx.x / NSLICE;
    const int s    = blockIdx.x % NSLICE;
    const int base = r << RANGE_LOG;
    const int len  = min(RANGE, N - base);

    for (int i = threadIdx.x; i < RANGE; i += P1_BLK) acc[i] = 0.0f;
    __syncthreads();

    const int segPer = (G + NSLICE - 1) / NSLICE;
    const int g0 = s * segPer;
    const int g1 = min(G, g0 + segPer);

    for (int g = g0; g < g1; ++g) {
        const int c = cnt[r * G + g];
        const unsigned* p = bins + ((size_t)r * G + g) * CAP;
        for (int j = threadIdx.x; j < c; j += P1_BLK) {
            unsigned e = p[j];
            int   lo  = (int)(e >> 17);
            float mag = __half2float(__ushort_as_half((unsigned short)(e & 0xFFFFu)));
            atomicAdd(&acc[lo], (e & 0x10000u) ? -mag : mag);
        }
    }

    __syncthreads();
    float* op = partial + (size_t)s * N + base;
    const int len4 = len & ~3;
    for (int i = (int)threadIdx.x * 4; i < len4; i += P1_BLK * 4)
        *(float4*)(op + i) = *(const float4*)&acc[i];
    for (int i = len4 + (int)threadIdx.x; i < len; i += P1_BLK)
        op[i] = acc[i];
}

__global__ __launch_bounds__(256) void reduce_kernel(
    const float* __restrict__ partial, float* __restrict__ out, int N4)
{
    int n = blockIdx.x * blockDim.x + threadIdx.x;
    if (n < N4) {
        float4 sm = make_float4(0.f, 0.f, 0.f, 0.f);
        for (int p = 0; p < NSLICE; ++p) {
            float4 q = ((const float4*)partial)[(size_t)p * N4 + n];
            sm.x += q.x; sm.y += q.y; sm.z += q.z; sm.w += q.w;
        }
        ((float4*)out)[n] = sm;
    }
}

__global__ __launch_bounds__(256) void reduce_scalar_kernel(
    const float* __restrict__ partial, float* __restrict__ out, int N)
{
    int n = blockIdx.x * blockDim.x + threadIdx.x;
    if (n < N) {
        float sm = 0.0f;
        for (int p = 0; p < NSLICE; ++p) sm += partial[(size_t)p * N + n];
        out[n] = sm;
    }
}

// fallback (ws too small / N too big): direct global atomics, slow but correct
__global__ __launch_bounds__(256) void atomic_fallback_kernel(
    const float* __restrict__ v, const int* __restrict__ src, const int* __restrict__ dst,
    const float* __restrict__ t1, const float* __restrict__ t2, const float* __restrict__ cond,
    float* __restrict__ out, int E)
{
    int i = blockIdx.x * blockDim.x + threadIdx.x;
    int stride = gridDim.x * blockDim.x;
    for (; i < E; i += stride) {
        int s = src[i], d = dst[i];
        float x = fmaf(t1[i], v[s] - v[d], t2[i]);
        if (x > 0.0f) {
            float c = cond[i] * x;
            atomicAdd(&out[d], c);
            atomicAdd(&out[s], -c);
        }
    }
}

extern "C" void kernel_launch(void* const* d_in, const int* in_sizes, int n_in,
                              void* d_out, int out_size, void* d_ws, size_t ws_size,
                              hipStream_t stream) {
    // inputs: t(0), v(1), src(2), dst(3), theta_sd_1(4), theta_sd_2(5), conductance(6)
    const float* v    = (const float*)d_in[1];
    const int*   src  = (const int*)  d_in[2];
    const int*   dst  = (const int*)  d_in[3];
    const float* t1   = (const float*)d_in[4];
    const float* t2   = (const float*)d_in[5];
    const float* cond = (const float*)d_in[6];
    float* out = (float*)d_out;
    const int E = in_sizes[2];
    const int N = out_size;

    const int G = (E + P0_EPB - 1) / P0_EPB;

    const size_t binBytes = ((size_t)NBIN * G * CAP * 4 + 255) & ~(size_t)255;
    const size_t cntBytes = ((size_t)NBIN * G * 4 + 255) & ~(size_t)255;
    const size_t parBytes = (size_t)NSLICE * N * sizeof(float);

    const bool ok = (N <= NBIN * RANGE) &&
                    (binBytes + cntBytes + parBytes <= ws_size);

    if (ok) {
        unsigned* bins    = (unsigned*)d_ws;
        int*      cnt     = (int*)((char*)d_ws + binBytes);
        float*    partial = (float*)((char*)d_ws + binBytes + cntBytes);

        p0_bin_kernel<<<G, P0_BLK, 0, stream>>>(v, src, dst, t1, t2, cond,
                                                bins, cnt, E, G);

        const int R = (N + RANGE - 1) / RANGE;   // <= NBIN
        p1_accum_kernel<<<R * NSLICE, P1_BLK, 0, stream>>>(bins, cnt, partial, N, G);

        if ((N & 3) == 0) {
            int n4 = N / 4;
            reduce_kernel<<<(n4 + 255) / 256, 256, 0, stream>>>(partial, out, n4);
        } else {
            reduce_scalar_kernel<<<(N + 255) / 256, 256, 0, stream>>>(partial, out, N);
        }
    } else {
        hipMemsetAsync(out, 0, (size_t)N * sizeof(float), stream);
        int grid = (E + 255) / 256;
        if (grid > 2048) grid = 2048;
        atomic_fallback_kernel<<<grid, 256, 0, stream>>>(v, src, dst, t1, t2, cond, out, E);
    }
}

// Round 7
// 75.960 us; speedup vs baseline: 1.1753x; 1.1753x over previous
//
#include <hip/hip_runtime.h>
#include <hip/hip_fp16.h>

// KirchhoffNet: out[n] = sum_{dst==n} cur - sum_{src==n} cur,
// cur = cond * relu(t1*(v[src]-v[dst]) + t2)
//
// Round 7: binned-entry pipeline, zero global atomics.
//  P0: stream edges, gather v, compute cur; emit packed entry
//      (local14|sign1|f16mag) per nonzero endpoint into 8 node-range bins
//      (LDS-staged, flushed to fixed per-(block,bin) slots).
//  P1: per (range, slice): 64KiB LDS acc (2 blk/CU), counts prefetched to
//      LDS, WAVE-PER-GROUP so 16 latency chains run concurrently per block.
//  P2: reduce NSLICE partial copies.

#define RANGE_LOG 14
#define RANGE     (1 << RANGE_LOG)      // 16384 nodes per range
#define NBIN      8                     // covers N <= 131072
#define P0_BLK    256
#define P0_EPT    4
#define P0_EPB    (P0_BLK * P0_EPT)     // 1024 edges per block
#define CAP       (2 * P0_EPB)          // 2048: worst-case entries/(block,bin)
#define P1_BLK    1024
#define NSLICE    32
#define MAXSEG    256                   // >= ceil(G/NSLICE)

__global__ __launch_bounds__(P0_BLK) void p0_bin_kernel(
    const float* __restrict__ v,
    const int*   __restrict__ src,
    const int*   __restrict__ dst,
    const float* __restrict__ t1,
    const float* __restrict__ t2,
    const float* __restrict__ cond,
    unsigned*    __restrict__ bins,   // [NBIN][G][CAP]
    int*         __restrict__ cnt,    // [NBIN][G]
    int E, int G)
{
    __shared__ unsigned sbuf[NBIN][CAP];   // 64 KiB
    __shared__ int scnt[NBIN];

    if (threadIdx.x < NBIN) scnt[threadIdx.x] = 0;
    __syncthreads();

    const int blk = blockIdx.x;
    const int i0  = blk * P0_EPB + (int)threadIdx.x * P0_EPT;

    #define EMIT(node, mag, signbit)                                        \
        {                                                                   \
            int rr = (node) >> RANGE_LOG;                                   \
            unsigned lo = (unsigned)((node) & (RANGE - 1));                 \
            unsigned hb = (unsigned)__half_as_ushort(__float2half(mag));    \
            unsigned en = (lo << 17) | ((unsigned)(signbit) << 16) | hb;    \
            int idx = atomicAdd(&scnt[rr], 1);                              \
            sbuf[rr][idx] = en;                                             \
        }

    if (i0 + P0_EPT <= E) {
        int4   s4 = *(const int4*)  (src  + i0);
        int4   d4 = *(const int4*)  (dst  + i0);
        float4 a4 = *(const float4*)(t1   + i0);
        float4 b4 = *(const float4*)(t2   + i0);
        float4 c4 = *(const float4*)(cond + i0);

        float vs0 = v[s4.x], vs1 = v[s4.y], vs2 = v[s4.z], vs3 = v[s4.w];
        float vd0 = v[d4.x], vd1 = v[d4.y], vd2 = v[d4.z], vd3 = v[d4.w];

        float x0 = fmaf(a4.x, vs0 - vd0, b4.x);
        float x1 = fmaf(a4.y, vs1 - vd1, b4.y);
        float x2 = fmaf(a4.z, vs2 - vd2, b4.z);
        float x3 = fmaf(a4.w, vs3 - vd3, b4.w);

        if (x0 > 0.0f) { float c = c4.x * x0; EMIT(d4.x, c, 0u) EMIT(s4.x, c, 1u) }
        if (x1 > 0.0f) { float c = c4.y * x1; EMIT(d4.y, c, 0u) EMIT(s4.y, c, 1u) }
        if (x2 > 0.0f) { float c = c4.z * x2; EMIT(d4.z, c, 0u) EMIT(s4.z, c, 1u) }
        if (x3 > 0.0f) { float c = c4.w * x3; EMIT(d4.w, c, 0u) EMIT(s4.w, c, 1u) }
    } else {
        for (int i = i0; i < E; ++i) {
            int s = src[i], d = dst[i];
            float x = fmaf(t1[i], v[s] - v[d], t2[i]);
            if (x > 0.0f) { float c = cond[i] * x; EMIT(d, c, 0u) EMIT(s, c, 1u) }
        }
    }
    #undef EMIT

    __syncthreads();
    for (int r = 0; r < NBIN; ++r) {
        int c = scnt[r];
        unsigned* g = bins + ((size_t)r * G + blk) * CAP;
        for (int j = threadIdx.x; j < c; j += P0_BLK) g[j] = sbuf[r][j];
    }
    if (threadIdx.x < NBIN) cnt[threadIdx.x * G + blk] = scnt[threadIdx.x];
}

__global__ __launch_bounds__(P1_BLK) void p1_accum_kernel(
    const unsigned* __restrict__ bins,   // [NBIN][G][CAP]
    const int*      __restrict__ cnt,    // [NBIN][G]
    float*          __restrict__ partial,// [NSLICE][N]
    int N, int G)
{
    __shared__ __align__(16) float acc[RANGE];   // 64 KiB
    __shared__ int scnt2[MAXSEG];

    const int r    = blockIdx.x / NSLICE;
    const int s    = blockIdx.x % NSLICE;
    const int base = r << RANGE_LOG;
    const int len  = min(RANGE, N - base);

    const int segPer = (G + NSLICE - 1) / NSLICE;
    const int g0 = s * segPer;
    const int g1 = min(G, g0 + segPer);
    const int ng = g1 - g0;

    for (int i = threadIdx.x; i < RANGE; i += P1_BLK) acc[i] = 0.0f;
    for (int i = threadIdx.x; i < ng; i += P1_BLK) scnt2[i] = cnt[r * G + g0 + i];
    __syncthreads();

    // wave-per-group: 16 independent latency chains per block
    const int wave = threadIdx.x >> 6;
    const int lane = threadIdx.x & 63;
    const int NW   = P1_BLK / 64;

    for (int gi = wave; gi < ng; gi += NW) {
        const int c = scnt2[gi];
        const unsigned* p = bins + ((size_t)r * G + (g0 + gi)) * CAP;
        for (int j = lane; j < c; j += 64) {
            unsigned e = p[j];
            int   lo  = (int)(e >> 17);
            float mag = __half2float(__ushort_as_half((unsigned short)(e & 0xFFFFu)));
            atomicAdd(&acc[lo], (e & 0x10000u) ? -mag : mag);
        }
    }

    __syncthreads();
    float* op = partial + (size_t)s * N + base;
    const int len4 = len & ~3;
    for (int i = (int)threadIdx.x * 4; i < len4; i += P1_BLK * 4)
        *(float4*)(op + i) = *(const float4*)&acc[i];
    for (int i = len4 + (int)threadIdx.x; i < len; i += P1_BLK)
        op[i] = acc[i];
}

__global__ __launch_bounds__(256) void reduce_kernel(
    const float* __restrict__ partial, float* __restrict__ out, int N4)
{
    int n = blockIdx.x * blockDim.x + threadIdx.x;
    if (n < N4) {
        float4 sm = make_float4(0.f, 0.f, 0.f, 0.f);
        for (int p = 0; p < NSLICE; ++p) {
            float4 q = ((const float4*)partial)[(size_t)p * N4 + n];
            sm.x += q.x; sm.y += q.y; sm.z += q.z; sm.w += q.w;
        }
        ((float4*)out)[n] = sm;
    }
}

__global__ __launch_bounds__(256) void reduce_scalar_kernel(
    const float* __restrict__ partial, float* __restrict__ out, int N)
{
    int n = blockIdx.x * blockDim.x + threadIdx.x;
    if (n < N) {
        float sm = 0.0f;
        for (int p = 0; p < NSLICE; ++p) sm += partial[(size_t)p * N + n];
        out[n] = sm;
    }
}

// fallback (ws too small / N too big): direct global atomics
__global__ __launch_bounds__(256) void atomic_fallback_kernel(
    const float* __restrict__ v, const int* __restrict__ src, const int* __restrict__ dst,
    const float* __restrict__ t1, const float* __restrict__ t2, const float* __restrict__ cond,
    float* __restrict__ out, int E)
{
    int i = blockIdx.x * blockDim.x + threadIdx.x;
    int stride = gridDim.x * blockDim.x;
    for (; i < E; i += stride) {
        int s = src[i], d = dst[i];
        float x = fmaf(t1[i], v[s] - v[d], t2[i]);
        if (x > 0.0f) {
            float c = cond[i] * x;
            atomicAdd(&out[d], c);
            atomicAdd(&out[s], -c);
        }
    }
}

extern "C" void kernel_launch(void* const* d_in, const int* in_sizes, int n_in,
                              void* d_out, int out_size, void* d_ws, size_t ws_size,
                              hipStream_t stream) {
    // inputs: t(0), v(1), src(2), dst(3), theta_sd_1(4), theta_sd_2(5), conductance(6)
    const float* v    = (const float*)d_in[1];
    const int*   src  = (const int*)  d_in[2];
    const int*   dst  = (const int*)  d_in[3];
    const float* t1   = (const float*)d_in[4];
    const float* t2   = (const float*)d_in[5];
    const float* cond = (const float*)d_in[6];
    float* out = (float*)d_out;
    const int E = in_sizes[2];
    const int N = out_size;

    const int G = (E + P0_EPB - 1) / P0_EPB;

    const size_t binBytes = ((size_t)NBIN * G * CAP * 4 + 255) & ~(size_t)255;
    const size_t cntBytes = ((size_t)NBIN * G * 4 + 255) & ~(size_t)255;
    const size_t parBytes = (size_t)NSLICE * N * sizeof(float);

    const bool ok = (N <= NBIN * RANGE) &&
                    ((G + NSLICE - 1) / NSLICE <= MAXSEG) &&
                    (binBytes + cntBytes + parBytes <= ws_size);

    if (ok) {
        unsigned* bins    = (unsigned*)d_ws;
        int*      cnt     = (int*)((char*)d_ws + binBytes);
        float*    partial = (float*)((char*)d_ws + binBytes + cntBytes);

        p0_bin_kernel<<<G, P0_BLK, 0, stream>>>(v, src, dst, t1, t2, cond,
                                                bins, cnt, E, G);

        const int R = (N + RANGE - 1) / RANGE;   // <= NBIN
        p1_accum_kernel<<<R * NSLICE, P1_BLK, 0, stream>>>(bins, cnt, partial, N, G);

        if ((N & 3) == 0) {
            int n4 = N / 4;
            reduce_kernel<<<(n4 + 255) / 256, 256, 0, stream>>>(partial, out, n4);
        } else {
            reduce_scalar_kernel<<<(N + 255) / 256, 256, 0, stream>>>(partial, out, N);
        }
    } else {
        hipMemsetAsync(out, 0, (size_t)N * sizeof(float), stream);
        int grid = (E + 255) / 256;
        if (grid > 2048) grid = 2048;
        atomic_fallback_kernel<<<grid, 256, 0, stream>>>(v, src, dst, t1, t2, cond, out, E);
    }
}